// Round 6
// baseline (194.704 us; speedup 1.0000x reference)
//
#include <hip/hip_runtime.h>

// VQ-VAE vector quantize + losses, MI355X.
// T=8192 rows, N_E=16384 codes, D=32.
// R21: R18/R20 triangulation — invariant ~55us wall = per-CU B-operand
//      byte flow: 16 rows/wave => 4MB/CU through the shared L1/LDS pipe
//      (~64-85 B/cyc => 20-27us floor). Fix: 64 rows(codes)/wave (4 A-frag
//      pairs resident) => B-traffic /4 (~1MB/CU). Register cost paid by
//      dropping the per-row a02 bias: rows are unit-normalized so a02 ~
//      const NS2F, and per-row constants cancel in softmax EXACTLY =>
//      pass1 bias = 80+2*NS2F (const), zred sc2g = (80+NS2F) - log2(Z);
//      k_mf exact refine still uses true a02/ses2. Block = 4wv x 64 rows;
//      NS1=32/RS2=16 => grids 1024 = 4 blocks/CU; launch_bounds (256,4)
//      (128-reg band, proven no-spill). gload_lds 2-phase dbuf kept (8KB).
//      Tripwires: pass1 WRITE ~5.2MB expected (2x splits); >>6MB = spill.

#define N_E 16384
#define ED 32
#define T 8192
#define NS1 32      // pass-1 code splits (512 codes each)
#define RS2 16      // pass-2 row splits  (512 rows each)
#define SKIPM -36.0f
#define PHT 2       // tiles per staged phase (4KB)

#define K2 288.53900817779268f      // 200 * log2(e)
#define NS2F -144.26950408889634f   // -100 * log2(e)
#define BIAS1 -208.53900817779268f  // 80 + 2*NS2F
#define SC2C -64.26950408889634f    // 80 + NS2F
#define LN2 0.6931471805599453f

typedef __attribute__((ext_vector_type(8))) short s16x8;
typedef __attribute__((ext_vector_type(4))) float f32x4;

__device__ __forceinline__ float fexp2(float x) { return __builtin_amdgcn_exp2f(x); }
__device__ __forceinline__ float flog2(float x) { return __builtin_amdgcn_logf(x); }
__device__ __forceinline__ float fmed3(float a, float b, float c) {
  return __builtin_amdgcn_fmed3f(a, b, c);
}

// async global->LDS, 16B per lane; LDS dest = wave-uniform base + lane*16.
__device__ __forceinline__ void gload16(const void* g, void* l) {
  __builtin_amdgcn_global_load_lds(
      (const __attribute__((address_space(1))) void*)g,
      (__attribute__((address_space(3))) void*)l, 16, 0, 0);
}

__device__ __forceinline__ unsigned short f2bf(float x) {
  unsigned u = __float_as_uint(x);
  unsigned r = (u + 0x7FFFu + ((u >> 16) & 1u)) >> 16;
  return (unsigned short)r;
}
__device__ __forceinline__ float bf2f(unsigned short h) {
  return __uint_as_float(((unsigned)h) << 16);
}

// exact fp32 dot of a streamed row with 8 resident float4s (by value)
__device__ __forceinline__ float dot32x(const float* __restrict__ p,
    float4 z0, float4 z1, float4 z2, float4 z3,
    float4 z4, float4 z5, float4 z6, float4 z7) {
  const float4* e = (const float4*)p;
  float a0 = 0.f, a1 = 0.f, a2 = 0.f, a3 = 0.f; float4 q;
  q = e[0]; a0 = fmaf(q.x, z0.x, a0); a0 = fmaf(q.y, z0.y, a0);
            a0 = fmaf(q.z, z0.z, a0); a0 = fmaf(q.w, z0.w, a0);
  q = e[1]; a1 = fmaf(q.x, z1.x, a1); a1 = fmaf(q.y, z1.y, a1);
            a1 = fmaf(q.z, z1.z, a1); a1 = fmaf(q.w, z1.w, a1);
  q = e[2]; a2 = fmaf(q.x, z2.x, a2); a2 = fmaf(q.y, z2.y, a2);
            a2 = fmaf(q.z, z2.z, a2); a2 = fmaf(q.w, z2.w, a2);
  q = e[3]; a3 = fmaf(q.x, z3.x, a3); a3 = fmaf(q.y, z3.y, a3);
            a3 = fmaf(q.z, z3.z, a3); a3 = fmaf(q.w, z3.w, a3);
  q = e[4]; a0 = fmaf(q.x, z4.x, a0); a0 = fmaf(q.y, z4.y, a0);
            a0 = fmaf(q.z, z4.z, a0); a0 = fmaf(q.w, z4.w, a0);
  q = e[5]; a1 = fmaf(q.x, z5.x, a1); a1 = fmaf(q.y, z5.y, a1);
            a1 = fmaf(q.z, z5.z, a1); a1 = fmaf(q.w, z5.w, a1);
  q = e[6]; a2 = fmaf(q.x, z6.x, a2); a2 = fmaf(q.y, z6.y, a2);
            a2 = fmaf(q.z, z6.z, a2); a2 = fmaf(q.w, z6.w, a2);
  q = e[7]; a3 = fmaf(q.x, z7.x, a3); a3 = fmaf(q.y, z7.y, a3);
            a3 = fmaf(q.z, z7.z, a3); a3 = fmaf(q.w, z7.w, a3);
  return (a0 + a1) + (a2 + a3);
}

// split 8 floats (scaled by sc) of row `row`, group g into hi/lo bf16 frags,
// stored TILE-MAJOR: dst[tile*128 + g*16 + c] (hi), +64 (lo); s16x8 units.
__device__ __forceinline__ void split_store_t(short* __restrict__ base,
    int row, int g, float4 va, float4 vb, float sc) {
  float f[8] = { va.x * sc, va.y * sc, va.z * sc, va.w * sc,
                 vb.x * sc, vb.y * sc, vb.z * sc, vb.w * sc };
  s16x8 H, L;
#pragma unroll
  for (int e = 0; e < 8; ++e) {
    unsigned short h = f2bf(f[e]);
    H[e] = (short)h;
    L[e] = (short)f2bf(f[e] - bf2f(h));
  }
  s16x8* p = (s16x8*)base;
  const int tile = row >> 4, c = row & 15;
  p[tile * 128 + g * 16 + c] = H;
  p[tile * 128 + 64 + g * 16 + c] = L;
}

// --- prep: blocks 0..63 emb rows; 64..95 z transpose; 96..160 zero avg/scal ---
__global__ __launch_bounds__(256) void k_prep(const float* __restrict__ emb,
    const float* __restrict__ z, float* __restrict__ embn,
    float* __restrict__ ses2, float* __restrict__ zf, float* __restrict__ a02,
    short* __restrict__ ehl, short* __restrict__ zhl, float* __restrict__ avg,
    float* __restrict__ scal) {
  if (blockIdx.x < 64) {
    int n = blockIdx.x * 256 + threadIdx.x;
    const float4* r4 = (const float4*)(emb + (size_t)n * ED);
    float4 v[8]; float s = 0.f;
#pragma unroll
    for (int j = 0; j < 8; ++j) {
      v[j] = r4[j];
      s = fmaf(v[j].x, v[j].x, s); s = fmaf(v[j].y, v[j].y, s);
      s = fmaf(v[j].z, v[j].z, s); s = fmaf(v[j].w, v[j].w, s);
    }
    float inv = 1.0f / fmaxf(sqrtf(s), 1e-12f);
    float s2 = 0.f;
    float4* o4 = (float4*)(embn + (size_t)n * ED);
#pragma unroll
    for (int j = 0; j < 8; ++j) {
      float4 w; w.x = v[j].x * inv; w.y = v[j].y * inv;
      w.z = v[j].z * inv; w.w = v[j].w * inv;
      o4[j] = w; v[j] = w;
      s2 = fmaf(w.x, w.x, s2); s2 = fmaf(w.y, w.y, s2);
      s2 = fmaf(w.z, w.z, s2); s2 = fmaf(w.w, w.w, s2);
    }
    ses2[n] = NS2F * s2;               // true value, for the exact refine
#pragma unroll
    for (int g = 0; g < 4; ++g)
      split_store_t(ehl, n, g, v[2 * g], v[2 * g + 1], 1.0f);
  } else if (blockIdx.x < 96) {
    int t = (blockIdx.x - 64) * 256 + threadIdx.x;
    int b = t >> 8, hw = t & 255;
    const float* base = z + (size_t)b * (ED * 256) + hw;
    float4 v[8]; float s = 0.f;
#pragma unroll
    for (int j = 0; j < 8; ++j) {
      float4 w;
      w.x = base[(4 * j + 0) * 256]; w.y = base[(4 * j + 1) * 256];
      w.z = base[(4 * j + 2) * 256]; w.w = base[(4 * j + 3) * 256];
      v[j] = w;
      s = fmaf(w.x, w.x, s); s = fmaf(w.y, w.y, s);
      s = fmaf(w.z, w.z, s); s = fmaf(w.w, w.w, s);
    }
    float inv = 1.0f / fmaxf(sqrtf(s), 1e-12f);
    float s2 = 0.f;
    float4* o4 = (float4*)(zf + (size_t)t * ED);
#pragma unroll
    for (int j = 0; j < 8; ++j) {
      float4 w; w.x = v[j].x * inv; w.y = v[j].y * inv;
      w.z = v[j].z * inv; w.w = v[j].w * inv;
      o4[j] = w; v[j] = w;
      s2 = fmaf(w.x, w.x, s2); s2 = fmaf(w.y, w.y, s2);
      s2 = fmaf(w.z, w.z, s2); s2 = fmaf(w.w, w.w, s2);
    }
    a02[t] = NS2F * s2;               // only k_mf (exact refine) uses this now
#pragma unroll
    for (int g = 0; g < 4; ++g)
      split_store_t(zhl, t, g, v[2 * g], v[2 * g + 1], K2);
  } else if (blockIdx.x < 160) {
    avg[(blockIdx.x - 96) * 256 + threadIdx.x] = 0.f;
  } else {
    if (threadIdx.x < 4) scal[threadIdx.x] = 0.f;  // [0]=sampE [1]=vq [2]=cnt
  }
}

// --- pass 1: block = 256 rows (4 waves x 64 rows = 4 A-pairs each), sweeps
//     a 512-code split (32 tiles, 16 phases x 2). B staged via gload_lds
//     into 2x4KB dbuf, shared by all 4 waves -> B-bytes/CU ~1MB. Bias is
//     the CONSTANT 80+2*NS2F (a02 ~ const; per-row consts cancel in
//     softmax). Top-2 via mantissa-packed keys, tu in low 6 bits. ---
__global__ __launch_bounds__(256, 4) void k_pass1(
    const short* __restrict__ ehl, const short* __restrict__ zhl,
    float* __restrict__ pm1, float* __restrict__ pm2, float* __restrict__ pZ,
    int* __restrict__ pi1, int* __restrict__ pi2) {
  const int tid = threadIdx.x;
  const int lane = tid & 63, wv = tid >> 6;
  const int q = lane >> 4, c = lane & 15;
  const int rowbase = blockIdx.x * 256 + wv * 64;
  const int nb0 = blockIdx.y * (N_E / NS1);
  const int NT = (N_E / NS1) / 16;  // 32
  const int NP = NT / PHT;          // 16

  __shared__ s16x8 dbuf[2][PHT * 128];   // 2 x 4KB

  const s16x8* zg = (const s16x8*)zhl;
  const int atile = rowbase >> 4;
  s16x8 ah[4], al[4];
#pragma unroll
  for (int rg = 0; rg < 4; ++rg) {
    ah[rg] = zg[(atile + rg) * 128 + lane];
    al[rg] = zg[(atile + rg) * 128 + 64 + lane];
  }

  f32x4 bias;
#pragma unroll
  for (int r = 0; r < 4; ++r) bias[r] = BIAS1;

  float m1[4][4], m2[4][4], Zs[4][4];
#pragma unroll
  for (int rg = 0; rg < 4; ++rg)
#pragma unroll
    for (int k = 0; k < 4; ++k) {
      m1[rg][k] = -1e30f; m2[rg][k] = -1e30f; Zs[rg][k] = 0.f;
    }

  const s16x8* eg = (const s16x8*)ehl + (size_t)(nb0 >> 4) * 128;

  // stage phase 0: 4KB, 1KB per wave (linear copy, layout-preserving)
  gload16(eg + wv * 64 + lane, &dbuf[0][wv * 64]);
  __syncthreads();

  for (int p = 0; p < NP; ++p) {
    if (p + 1 < NP)
      gload16(eg + (p + 1) * (PHT * 128) + wv * 64 + lane,
              &dbuf[(p + 1) & 1][wv * 64]);
    const s16x8* bb = &dbuf[p & 1][0];
#pragma unroll
    for (int tt = 0; tt < PHT; ++tt) {
      s16x8 bh = bb[tt * 128 + lane], bl = bb[tt * 128 + 64 + lane];
      const unsigned tu = (unsigned)(p * PHT + tt);       // 0..31, 6-bit field
#pragma unroll
      for (int rg = 0; rg < 4; ++rg) {
        f32x4 acc = __builtin_amdgcn_mfma_f32_16x16x32_bf16(ah[rg], bh, bias, 0, 0, 0);
        acc = __builtin_amdgcn_mfma_f32_16x16x32_bf16(al[rg], bh, acc, 0, 0, 0);
        acc = __builtin_amdgcn_mfma_f32_16x16x32_bf16(ah[rg], bl, acc, 0, 0, 0);
#pragma unroll
        for (int r = 0; r < 4; ++r) {
          float fb = acc[r];
          float key = __uint_as_float((__float_as_uint(fb) & 0xFFFFFFC0u) | tu);
          m2[rg][r] = fmed3(key, m1[rg][r], m2[rg][r]);
          m1[rg][r] = fmaxf(m1[rg][r], key);
          Zs[rg][r] += fexp2(fb);
        }
      }
    }
    __syncthreads();
  }

  // decode indices from this lane's own keys (c local), then reduce over c
  int i1[4][4], i2[4][4];
#pragma unroll
  for (int rg = 0; rg < 4; ++rg)
#pragma unroll
    for (int k = 0; k < 4; ++k) {
      i1[rg][k] = nb0 + (int)((__float_as_uint(m1[rg][k]) & 63u) << 4) + c;
      i2[rg][k] = nb0 + (int)((__float_as_uint(m2[rg][k]) & 63u) << 4) + c;
    }

#pragma unroll
  for (int d = 1; d < 16; d <<= 1) {
#pragma unroll
    for (int rg = 0; rg < 4; ++rg)
#pragma unroll
      for (int k = 0; k < 4; ++k) {
        float om1 = __shfl_xor(m1[rg][k], d);
        float om2 = __shfl_xor(m2[rg][k], d);
        float oZ = __shfl_xor(Zs[rg][k], d);
        int oi1 = __shfl_xor(i1[rg][k], d);
        int oi2 = __shfl_xor(i2[rg][k], d);
        bool c1 = om1 > m1[rg][k];
        float lm = c1 ? m1[rg][k] : om1;
        int li = c1 ? i1[rg][k] : oi1;
        float nm1 = c1 ? om1 : m1[rg][k];
        int ni1 = c1 ? oi1 : i1[rg][k];
        bool cb = om2 > m2[rg][k];
        float mm2 = cb ? om2 : m2[rg][k];
        int mi2 = cb ? oi2 : i2[rg][k];
        bool c3 = mm2 > lm;
        m1[rg][k] = nm1; i1[rg][k] = ni1;
        m2[rg][k] = c3 ? mm2 : lm;
        i2[rg][k] = c3 ? mi2 : li;
        Zs[rg][k] += oZ;
      }
  }

#pragma unroll
  for (int rg = 0; rg < 4; ++rg)
#pragma unroll
    for (int k = 0; k < 4; ++k) {
      if (c == k) {
        const int t = rowbase + rg * 16 + q * 4 + k;
        const int p = blockIdx.y * T + t;
        pm1[p] = m1[rg][k]; pm2[p] = m2[rg][k]; pZ[p] = Zs[rg][k];
        pi1[p] = i1[rg][k]; pi2[p] = i2[rg][k];
      }
    }
}

// --- zred: per-row Z merge + lse shift (bias-free form), once. ---
__global__ __launch_bounds__(256) void k_zred(const float* __restrict__ pZ,
    float* __restrict__ sc2g) {
  const int t = blockIdx.x * 256 + threadIdx.x;
  float Z = 0.f;
  for (int s = 0; s < NS1; ++s) Z += pZ[s * T + t];
  sc2g[t] = SC2C - flog2(Z);
}

// --- pass 2: block = 256 codes (4 waves x 64 codes = 4 A-pairs), sweeps a
//     512-row split. zhl staged via gload_lds (2x4KB dbuf); sc2 split (2KB)
//     staged once. Tile-skip per row-group: max(fb)+cc > -36. ---
__global__ __launch_bounds__(256, 4) void k_pass2(
    const short* __restrict__ ehl, const short* __restrict__ zhl,
    const float* __restrict__ sc2g,
    float* __restrict__ avg, float* __restrict__ scal) {
  const int tid = threadIdx.x;
  const int lane = tid & 63, wv = tid >> 6;
  const int q = lane >> 4, c = lane & 15;
  const int bx = blockIdx.x & 63, by = blockIdx.x >> 6;
  const int tb0 = by * (T / RS2);
  const int cbase = bx * 256 + wv * 64;
  const int NT = (T / RS2) / 16;    // 32
  const int NP = NT / PHT;          // 16

  __shared__ s16x8 dbuf[2][PHT * 128];   // 8KB
  __shared__ float sc2l[T / RS2];        // 512 f = 2KB

  if (tid < (T / RS2) / 4)
    ((float4*)sc2l)[tid] = ((const float4*)(sc2g + tb0))[tid];

  const s16x8* eg = (const s16x8*)ehl;
  const int atile = cbase >> 4;
  s16x8 ah[4], al[4];
#pragma unroll
  for (int rg = 0; rg < 4; ++rg) {
    ah[rg] = eg[(atile + rg) * 128 + lane];
    al[rg] = eg[(atile + rg) * 128 + 64 + lane];
  }

  f32x4 sg;
#pragma unroll
  for (int r = 0; r < 4; ++r) sg[r] = NS2F;

  float accP[4][4], accE[4][4];
#pragma unroll
  for (int rg = 0; rg < 4; ++rg)
#pragma unroll
    for (int k = 0; k < 4; ++k) { accP[rg][k] = 0.f; accE[rg][k] = 0.f; }

  const s16x8* zt = (const s16x8*)zhl + (size_t)(tb0 >> 4) * 128;

  gload16(zt + wv * 64 + lane, &dbuf[0][wv * 64]);
  __syncthreads();

  for (int p = 0; p < NP; ++p) {
    if (p + 1 < NP)
      gload16(zt + (p + 1) * (PHT * 128) + wv * 64 + lane,
              &dbuf[(p + 1) & 1][wv * 64]);
    const s16x8* bb = &dbuf[p & 1][0];
#pragma unroll
    for (int tt = 0; tt < PHT; ++tt) {
      s16x8 bh = bb[tt * 128 + lane], bl = bb[tt * 128 + 64 + lane];
      float cc = sc2l[(p * PHT + tt) * 16 + c];
#pragma unroll
      for (int rg = 0; rg < 4; ++rg) {
        f32x4 acc = __builtin_amdgcn_mfma_f32_16x16x32_bf16(ah[rg], bh, sg, 0, 0, 0);
        acc = __builtin_amdgcn_mfma_f32_16x16x32_bf16(al[rg], bh, acc, 0, 0, 0);
        acc = __builtin_amdgcn_mfma_f32_16x16x32_bf16(ah[rg], bl, acc, 0, 0, 0);

        float m4 = fmaxf(fmaxf(acc[0], acc[1]), fmaxf(acc[2], acc[3]));
        if (__any(m4 + cc > SKIPM)) {
#pragma unroll
          for (int r = 0; r < 4; ++r) {
            float dl = acc[r] + cc;   // fb - lse (<=0)
            float pe = fexp2(dl);     // underflow -> 0
            accP[rg][r] += pe;
            accE[rg][r] = fmaf(pe, dl, accE[rg][r]);
          }
        }
      }
    }
    __syncthreads();
  }

  float etot = 0.f;
#pragma unroll
  for (int rg = 0; rg < 4; ++rg)
#pragma unroll
    for (int k = 0; k < 4; ++k) etot += accE[rg][k];

#pragma unroll
  for (int d = 1; d < 16; d <<= 1) {
#pragma unroll
    for (int rg = 0; rg < 4; ++rg)
#pragma unroll
      for (int k = 0; k < 4; ++k) accP[rg][k] += __shfl_xor(accP[rg][k], d);
  }
#pragma unroll
  for (int rg = 0; rg < 4; ++rg)
#pragma unroll
    for (int k = 0; k < 4; ++k) {
      if (c == k) atomicAdd(&avg[cbase + rg * 16 + q * 4 + k], accP[rg][k]);
    }

  float* red = sc2l;                 // sweep done; reuse LDS (post-barrier)
  red[tid] = etot;
  __syncthreads();
  for (int st = 128; st > 0; st >>= 1) {
    if (tid < st) red[tid] += red[tid + st];
    __syncthreads();
  }
  if (tid == 0) atomicAdd(&scal[0], red[0]);
}

// --- merge-final: 32 blocks, thread = row. Top-2 combine, exact fp32
//     refine, vq sum + straight-through output; last block finals. ---
__global__ __launch_bounds__(256) void k_mf(
    const float* __restrict__ pm1, const float* __restrict__ pm2,
    const int* __restrict__ pi1, const int* __restrict__ pi2,
    const float* __restrict__ zf, const float* __restrict__ embn,
    const float* __restrict__ ses2, const float* __restrict__ a02,
    float* __restrict__ avg, float* __restrict__ scal, float* __restrict__ out) {
  const int tid = threadIdx.x;
  const int t = blockIdx.x * 256 + tid;
  __shared__ float red[256];
  __shared__ unsigned sord;

  float m1 = -1e30f, m2 = -1e30f;
  int i1 = 0, i2 = 0;
  for (int s = 0; s < NS1; ++s) {
    const int p = s * T + t;
    float sm1 = pm1[p], sm2 = pm2[p];
    int si1 = pi1[p], si2 = pi2[p];
    bool c1 = sm1 > m1;
    float lm = c1 ? m1 : sm1;
    int li = c1 ? i1 : si1;
    float nm1 = c1 ? sm1 : m1;
    int ni1 = c1 ? si1 : i1;
    bool cb = sm2 > m2;
    float mm2 = cb ? sm2 : m2;
    int mi2 = cb ? si2 : i2;
    bool c3 = mm2 > lm;
    m1 = nm1; i1 = ni1;
    m2 = c3 ? mm2 : lm;
    i2 = c3 ? mi2 : li;
  }
  const float a02t = a02[t];

  const float4* zr4 = (const float4*)(zf + (size_t)t * ED);
  float4 z0 = zr4[0], z1 = zr4[1], z2 = zr4[2], z3 = zr4[3];
  float4 z4 = zr4[4], z5 = zr4[5], z6 = zr4[6], z7 = zr4[7];
  float d1 = dot32x(embn + (size_t)i1 * ED, z0, z1, z2, z3, z4, z5, z6, z7);
  float d2 = dot32x(embn + (size_t)i2 * ED, z0, z1, z2, z3, z4, z5, z6, z7);
  float fb1 = fmaf(K2, d1, a02t + ses2[i1]);   // true a02/ses2: exact rule
  float fb2 = fmaf(K2, d2, a02t + ses2[i2]);
  int bi = (fb2 > fb1 || (fb2 == fb1 && i2 < i1)) ? i2 : i1;

  const int b = t >> 8, hw = t & 255;
  float* ob = out + (size_t)b * (ED * 256) + hw;
  float ss = 0.f;
  const float4* e4 = (const float4*)(embn + (size_t)bi * ED);
#pragma unroll
  for (int j = 0; j < 8; ++j) {
    float4 qv = e4[j];
    float4 zv = (j == 0) ? z0 : (j == 1) ? z1 : (j == 2) ? z2 : (j == 3) ? z3
              : (j == 4) ? z4 : (j == 5) ? z5 : (j == 6) ? z6 : z7;
    float df;
    df = qv.x - zv.x; ss = fmaf(df, df, ss); ob[(4 * j + 0) * 256] = zv.x + (qv.x - zv.x);
    df = qv.y - zv.y; ss = fmaf(df, df, ss); ob[(4 * j + 1) * 256] = zv.y + (qv.y - zv.y);
    df = qv.z - zv.z; ss = fmaf(df, df, ss); ob[(4 * j + 2) * 256] = zv.z + (qv.z - zv.z);
    df = qv.w - zv.w; ss = fmaf(df, df, ss); ob[(4 * j + 3) * 256] = zv.w + (qv.w - zv.w);
  }
  red[tid] = ss;
  __syncthreads();
  for (int st = 128; st > 0; st >>= 1) {
    if (tid < st) red[tid] += red[tid + st];
    __syncthreads();
  }
  if (tid == 0) atomicAdd(&scal[1], red[0]);

  // last-block final (avg/scal[0] were completed by the previous kernel)
  __threadfence();
  __syncthreads();
  if (tid == 0) sord = atomicAdd((unsigned*)&scal[2], 1u);
  __syncthreads();
  if (sord == 31) {
    float s = 0.f;
    for (int i = tid; i < N_E; i += 256) {
      float a = avg[i] * (1.0f / T);
      s += a * (flog2(a + 1e-5f) * LN2);
    }
    red[tid] = s;
    __syncthreads();
    for (int st = 128; st > 0; st >>= 1) {
      if (tid < st) red[tid] += red[tid + st];
      __syncthreads();
    }
    if (tid == 0) {
      float avg_entropy = -red[0];
      float se = scal[0];
      float vqs = __hip_atomic_load(&scal[1], __ATOMIC_RELAXED,
                                    __HIP_MEMORY_SCOPE_AGENT);
      float sample_entropy = -(se * LN2) * (1.0f / T);
      float vq = vqs * (1.0f / (T * ED));
      out[T * ED + 0] = vq;
      out[T * ED + 1] = 0.25f * vq;
      out[T * ED + 2] = 0.1f * (sample_entropy - avg_entropy);
    }
  }
}

extern "C" void kernel_launch(void* const* d_in, const int* in_sizes, int n_in,
                              void* d_out, int out_size, void* d_ws, size_t ws_size,
                              hipStream_t stream) {
  const float* z = (const float*)d_in[0];
  const float* emb = (const float*)d_in[1];
  float* out = (float*)d_out;
  float* w = (float*)d_ws;

  float* embn = w;                          // 524288 f
  float* ses2 = embn + 524288;              // 16384
  float* zf   = ses2 + 16384;               // 262144
  float* a02  = zf + 262144;                // 8192
  short* ehl  = (short*)(a02 + 8192);       // 1048576 sh (524288 f)
  short* zhl  = ehl + 1048576;              // 524288 sh  (262144 f)
  float* pm1  = (float*)(zhl + 524288);     // NS1*T = 262144 f
  float* pm2  = pm1 + NS1 * T;              // 262144
  float* pZ   = pm2 + NS1 * T;              // 262144
  int*   pi1  = (int*)(pZ + NS1 * T);       // 262144
  int*   pi2  = pi1 + NS1 * T;              // 262144
  float* avg  = (float*)(pi2 + NS1 * T);    // 16384
  float* scal = avg + 16384;                // 4: sampE, vq, counter, pad
  float* sc2g = scal + 4;                   // 8192

  k_prep<<<161, 256, 0, stream>>>(emb, z, embn, ses2, zf, a02, ehl, zhl,
                                  avg, scal);
  k_pass1<<<dim3(T / 256, NS1), 256, 0, stream>>>(ehl, zhl,
                                                  pm1, pm2, pZ, pi1, pi2);
  k_zred<<<T / 256, 256, 0, stream>>>(pZ, sc2g);
  k_pass2<<<(N_E / 256) * RS2, 256, 0, stream>>>(ehl, zhl, sc2g, avg, scal);
  k_mf<<<32, 256, 0, stream>>>(pm1, pm2, pi1, pi2, zf, embn, ses2, a02,
                               avg, scal, out);
}

// Round 7
// 173.170 us; speedup vs baseline: 1.1243x; 1.1243x over previous
//
#include <hip/hip_runtime.h>

// VQ-VAE vector quantize + losses, MI355X.
// T=8192 rows, N_E=16384 codes, D=32.
// R22: R21 spilled (live ~130 > 128 cap; WRITE 44MB) but its bias-fold math
//      verified (absmax unchanged). L2-BW theory now quantitative: private
//      per-wave B reads = 2GB L2 = 58us @ 34.5TB/s == the R15/R18 invariant
//      (L1 thrashes: co-resident blocks have different splits). R20 staging
//      cut bytes 4x but 1-phase-in-flight capped achieved BW at 9.5TB/s.
//      R22 = validated pieces, sized to fit:
//      - 32 rows(codes)/wave (2 A-pairs) x 4 waves = 128/block; live ~75
//        regs, fits (256,4)'s 128 cap. Epilogue unchanged ([2][4] is small).
//      - bias-folded constants (pass1 bias=80+2*NS2F; sc2g=(80+NS2F)-log2Z).
//      - gload_lds staging, PHT=8 (2x16KB dbuf): per-phase compute ~3.5K
//        cyc/SIMD >> load latency; 8 barriers/sweep. 4 blocks/CU.
//      - L2 traffic 256MB (8x less than R18). NS1=16.
//      Tripwires: WRITE ~2.5MB (spill); if >=45us clean -> L2 theory dead.

#define N_E 16384
#define ED 32
#define T 8192
#define NS1 16      // pass-1 code splits (1024 codes each)
#define RS2 8       // pass-2 row splits  (1024 rows each)
#define SKIPM -36.0f
#define PHT 8       // tiles per staged phase (16KB)

#define K2 288.53900817779268f      // 200 * log2(e)
#define NS2F -144.26950408889634f   // -100 * log2(e)
#define BIAS1 -208.53900817779268f  // 80 + 2*NS2F
#define SC2C -64.26950408889634f    // 80 + NS2F
#define LN2 0.6931471805599453f

typedef __attribute__((ext_vector_type(8))) short s16x8;
typedef __attribute__((ext_vector_type(4))) float f32x4;

__device__ __forceinline__ float fexp2(float x) { return __builtin_amdgcn_exp2f(x); }
__device__ __forceinline__ float flog2(float x) { return __builtin_amdgcn_logf(x); }
__device__ __forceinline__ float fmed3(float a, float b, float c) {
  return __builtin_amdgcn_fmed3f(a, b, c);
}

// async global->LDS, 16B per lane; LDS dest = wave-uniform base + lane*16.
__device__ __forceinline__ void gload16(const void* g, void* l) {
  __builtin_amdgcn_global_load_lds(
      (const __attribute__((address_space(1))) void*)g,
      (__attribute__((address_space(3))) void*)l, 16, 0, 0);
}

__device__ __forceinline__ unsigned short f2bf(float x) {
  unsigned u = __float_as_uint(x);
  unsigned r = (u + 0x7FFFu + ((u >> 16) & 1u)) >> 16;
  return (unsigned short)r;
}
__device__ __forceinline__ float bf2f(unsigned short h) {
  return __uint_as_float(((unsigned)h) << 16);
}

// exact fp32 dot of a streamed row with 8 resident float4s (by value)
__device__ __forceinline__ float dot32x(const float* __restrict__ p,
    float4 z0, float4 z1, float4 z2, float4 z3,
    float4 z4, float4 z5, float4 z6, float4 z7) {
  const float4* e = (const float4*)p;
  float a0 = 0.f, a1 = 0.f, a2 = 0.f, a3 = 0.f; float4 q;
  q = e[0]; a0 = fmaf(q.x, z0.x, a0); a0 = fmaf(q.y, z0.y, a0);
            a0 = fmaf(q.z, z0.z, a0); a0 = fmaf(q.w, z0.w, a0);
  q = e[1]; a1 = fmaf(q.x, z1.x, a1); a1 = fmaf(q.y, z1.y, a1);
            a1 = fmaf(q.z, z1.z, a1); a1 = fmaf(q.w, z1.w, a1);
  q = e[2]; a2 = fmaf(q.x, z2.x, a2); a2 = fmaf(q.y, z2.y, a2);
            a2 = fmaf(q.z, z2.z, a2); a2 = fmaf(q.w, z2.w, a2);
  q = e[3]; a3 = fmaf(q.x, z3.x, a3); a3 = fmaf(q.y, z3.y, a3);
            a3 = fmaf(q.z, z3.z, a3); a3 = fmaf(q.w, z3.w, a3);
  q = e[4]; a0 = fmaf(q.x, z4.x, a0); a0 = fmaf(q.y, z4.y, a0);
            a0 = fmaf(q.z, z4.z, a0); a0 = fmaf(q.w, z4.w, a0);
  q = e[5]; a1 = fmaf(q.x, z5.x, a1); a1 = fmaf(q.y, z5.y, a1);
            a1 = fmaf(q.z, z5.z, a1); a1 = fmaf(q.w, z5.w, a1);
  q = e[6]; a2 = fmaf(q.x, z6.x, a2); a2 = fmaf(q.y, z6.y, a2);
            a2 = fmaf(q.z, z6.z, a2); a2 = fmaf(q.w, z6.w, a2);
  q = e[7]; a3 = fmaf(q.x, z7.x, a3); a3 = fmaf(q.y, z7.y, a3);
            a3 = fmaf(q.z, z7.z, a3); a3 = fmaf(q.w, z7.w, a3);
  return (a0 + a1) + (a2 + a3);
}

// split 8 floats (scaled by sc) of row `row`, group g into hi/lo bf16 frags,
// stored TILE-MAJOR: dst[tile*128 + g*16 + c] (hi), +64 (lo); s16x8 units.
__device__ __forceinline__ void split_store_t(short* __restrict__ base,
    int row, int g, float4 va, float4 vb, float sc) {
  float f[8] = { va.x * sc, va.y * sc, va.z * sc, va.w * sc,
                 vb.x * sc, vb.y * sc, vb.z * sc, vb.w * sc };
  s16x8 H, L;
#pragma unroll
  for (int e = 0; e < 8; ++e) {
    unsigned short h = f2bf(f[e]);
    H[e] = (short)h;
    L[e] = (short)f2bf(f[e] - bf2f(h));
  }
  s16x8* p = (s16x8*)base;
  const int tile = row >> 4, c = row & 15;
  p[tile * 128 + g * 16 + c] = H;
  p[tile * 128 + 64 + g * 16 + c] = L;
}

// --- prep: blocks 0..63 emb rows; 64..95 z transpose; 96..160 zero avg/scal ---
__global__ __launch_bounds__(256) void k_prep(const float* __restrict__ emb,
    const float* __restrict__ z, float* __restrict__ embn,
    float* __restrict__ ses2, float* __restrict__ zf, float* __restrict__ a02,
    short* __restrict__ ehl, short* __restrict__ zhl, float* __restrict__ avg,
    float* __restrict__ scal) {
  if (blockIdx.x < 64) {
    int n = blockIdx.x * 256 + threadIdx.x;
    const float4* r4 = (const float4*)(emb + (size_t)n * ED);
    float4 v[8]; float s = 0.f;
#pragma unroll
    for (int j = 0; j < 8; ++j) {
      v[j] = r4[j];
      s = fmaf(v[j].x, v[j].x, s); s = fmaf(v[j].y, v[j].y, s);
      s = fmaf(v[j].z, v[j].z, s); s = fmaf(v[j].w, v[j].w, s);
    }
    float inv = 1.0f / fmaxf(sqrtf(s), 1e-12f);
    float s2 = 0.f;
    float4* o4 = (float4*)(embn + (size_t)n * ED);
#pragma unroll
    for (int j = 0; j < 8; ++j) {
      float4 w; w.x = v[j].x * inv; w.y = v[j].y * inv;
      w.z = v[j].z * inv; w.w = v[j].w * inv;
      o4[j] = w; v[j] = w;
      s2 = fmaf(w.x, w.x, s2); s2 = fmaf(w.y, w.y, s2);
      s2 = fmaf(w.z, w.z, s2); s2 = fmaf(w.w, w.w, s2);
    }
    ses2[n] = NS2F * s2;               // true value, for the exact refine
#pragma unroll
    for (int g = 0; g < 4; ++g)
      split_store_t(ehl, n, g, v[2 * g], v[2 * g + 1], 1.0f);
  } else if (blockIdx.x < 96) {
    int t = (blockIdx.x - 64) * 256 + threadIdx.x;
    int b = t >> 8, hw = t & 255;
    const float* base = z + (size_t)b * (ED * 256) + hw;
    float4 v[8]; float s = 0.f;
#pragma unroll
    for (int j = 0; j < 8; ++j) {
      float4 w;
      w.x = base[(4 * j + 0) * 256]; w.y = base[(4 * j + 1) * 256];
      w.z = base[(4 * j + 2) * 256]; w.w = base[(4 * j + 3) * 256];
      v[j] = w;
      s = fmaf(w.x, w.x, s); s = fmaf(w.y, w.y, s);
      s = fmaf(w.z, w.z, s); s = fmaf(w.w, w.w, s);
    }
    float inv = 1.0f / fmaxf(sqrtf(s), 1e-12f);
    float s2 = 0.f;
    float4* o4 = (float4*)(zf + (size_t)t * ED);
#pragma unroll
    for (int j = 0; j < 8; ++j) {
      float4 w; w.x = v[j].x * inv; w.y = v[j].y * inv;
      w.z = v[j].z * inv; w.w = v[j].w * inv;
      o4[j] = w; v[j] = w;
      s2 = fmaf(w.x, w.x, s2); s2 = fmaf(w.y, w.y, s2);
      s2 = fmaf(w.z, w.z, s2); s2 = fmaf(w.w, w.w, s2);
    }
    a02[t] = NS2F * s2;               // only k_mf (exact refine) uses this
#pragma unroll
    for (int g = 0; g < 4; ++g)
      split_store_t(zhl, t, g, v[2 * g], v[2 * g + 1], K2);
  } else if (blockIdx.x < 160) {
    avg[(blockIdx.x - 96) * 256 + threadIdx.x] = 0.f;
  } else {
    if (threadIdx.x < 4) scal[threadIdx.x] = 0.f;  // [0]=sampE [1]=vq [2]=cnt
  }
}

// --- pass 1: block = 128 rows (4 waves x 32 = 2 A-pairs each), sweeps a
//     1024-code split (64 tiles, 8 phases x 8). B staged via gload_lds
//     into 2x16KB dbuf shared by 4 waves -> L2 traffic 256MB total. Bias
//     is the CONSTANT 80+2*NS2F (a02~const; per-row consts cancel in
//     softmax; verified R21). Top-2 via mantissa-packed keys (tu 6-bit). ---
__global__ __launch_bounds__(256, 4) void k_pass1(
    const short* __restrict__ ehl, const short* __restrict__ zhl,
    float* __restrict__ pm1, float* __restrict__ pm2, float* __restrict__ pZ,
    int* __restrict__ pi1, int* __restrict__ pi2) {
  const int tid = threadIdx.x;
  const int lane = tid & 63, wv = tid >> 6;
  const int q = lane >> 4, c = lane & 15;
  const int rowbase = blockIdx.x * 128 + wv * 32;
  const int nb0 = blockIdx.y * (N_E / NS1);
  const int NT = (N_E / NS1) / 16;  // 64
  const int NP = NT / PHT;          // 8

  __shared__ s16x8 dbuf[2][PHT * 128];   // 2 x 16KB

  const s16x8* zg = (const s16x8*)zhl;
  const int atile = rowbase >> 4;
  s16x8 ah[2], al[2];
#pragma unroll
  for (int rg = 0; rg < 2; ++rg) {
    ah[rg] = zg[(atile + rg) * 128 + lane];
    al[rg] = zg[(atile + rg) * 128 + 64 + lane];
  }

  f32x4 bias;
#pragma unroll
  for (int r = 0; r < 4; ++r) bias[r] = BIAS1;

  float m1[2][4], m2[2][4], Zs[2][4];
#pragma unroll
  for (int rg = 0; rg < 2; ++rg)
#pragma unroll
    for (int k = 0; k < 4; ++k) {
      m1[rg][k] = -1e30f; m2[rg][k] = -1e30f; Zs[rg][k] = 0.f;
    }

  const s16x8* eg = (const s16x8*)ehl + (size_t)(nb0 >> 4) * 128;

  // stage phase 0: 16KB; wave wv covers s16x8 [wv*256, wv*256+256)
#pragma unroll
  for (int j = 0; j < 4; ++j)
    gload16(eg + wv * 256 + j * 64 + lane, &dbuf[0][wv * 256 + j * 64]);
  __syncthreads();

  for (int p = 0; p < NP; ++p) {
    if (p + 1 < NP) {
      const s16x8* gs = eg + (p + 1) * (PHT * 128);
      s16x8* lb = &dbuf[(p + 1) & 1][0];
#pragma unroll
      for (int j = 0; j < 4; ++j)
        gload16(gs + wv * 256 + j * 64 + lane, lb + wv * 256 + j * 64);
    }
    const s16x8* bb = &dbuf[p & 1][0];
#pragma unroll
    for (int tt = 0; tt < PHT; ++tt) {
      s16x8 bh = bb[tt * 128 + lane], bl = bb[tt * 128 + 64 + lane];
      const unsigned tu = (unsigned)(p * PHT + tt);       // 0..63, 6-bit
#pragma unroll
      for (int rg = 0; rg < 2; ++rg) {
        f32x4 acc = __builtin_amdgcn_mfma_f32_16x16x32_bf16(ah[rg], bh, bias, 0, 0, 0);
        acc = __builtin_amdgcn_mfma_f32_16x16x32_bf16(al[rg], bh, acc, 0, 0, 0);
        acc = __builtin_amdgcn_mfma_f32_16x16x32_bf16(ah[rg], bl, acc, 0, 0, 0);
#pragma unroll
        for (int r = 0; r < 4; ++r) {
          float fb = acc[r];
          float key = __uint_as_float((__float_as_uint(fb) & 0xFFFFFFC0u) | tu);
          m2[rg][r] = fmed3(key, m1[rg][r], m2[rg][r]);
          m1[rg][r] = fmaxf(m1[rg][r], key);
          Zs[rg][r] += fexp2(fb);
        }
      }
    }
    __syncthreads();
  }

  // decode indices from this lane's own keys (c local), then reduce over c
  int i1[2][4], i2[2][4];
#pragma unroll
  for (int rg = 0; rg < 2; ++rg)
#pragma unroll
    for (int k = 0; k < 4; ++k) {
      i1[rg][k] = nb0 + (int)((__float_as_uint(m1[rg][k]) & 63u) << 4) + c;
      i2[rg][k] = nb0 + (int)((__float_as_uint(m2[rg][k]) & 63u) << 4) + c;
    }

#pragma unroll
  for (int d = 1; d < 16; d <<= 1) {
#pragma unroll
    for (int rg = 0; rg < 2; ++rg)
#pragma unroll
      for (int k = 0; k < 4; ++k) {
        float om1 = __shfl_xor(m1[rg][k], d);
        float om2 = __shfl_xor(m2[rg][k], d);
        float oZ = __shfl_xor(Zs[rg][k], d);
        int oi1 = __shfl_xor(i1[rg][k], d);
        int oi2 = __shfl_xor(i2[rg][k], d);
        bool c1 = om1 > m1[rg][k];
        float lm = c1 ? m1[rg][k] : om1;
        int li = c1 ? i1[rg][k] : oi1;
        float nm1 = c1 ? om1 : m1[rg][k];
        int ni1 = c1 ? oi1 : i1[rg][k];
        bool cb = om2 > m2[rg][k];
        float mm2 = cb ? om2 : m2[rg][k];
        int mi2 = cb ? oi2 : i2[rg][k];
        bool c3 = mm2 > lm;
        m1[rg][k] = nm1; i1[rg][k] = ni1;
        m2[rg][k] = c3 ? mm2 : lm;
        i2[rg][k] = c3 ? mi2 : li;
        Zs[rg][k] += oZ;
      }
  }

#pragma unroll
  for (int rg = 0; rg < 2; ++rg)
#pragma unroll
    for (int k = 0; k < 4; ++k) {
      if (c == k) {
        const int t = rowbase + rg * 16 + q * 4 + k;
        const int p = blockIdx.y * T + t;
        pm1[p] = m1[rg][k]; pm2[p] = m2[rg][k]; pZ[p] = Zs[rg][k];
        pi1[p] = i1[rg][k]; pi2[p] = i2[rg][k];
      }
    }
}

// --- zred: per-row Z merge + lse shift (bias-free form), once. ---
__global__ __launch_bounds__(256) void k_zred(const float* __restrict__ pZ,
    float* __restrict__ sc2g) {
  const int t = blockIdx.x * 256 + threadIdx.x;
  float Z = 0.f;
  for (int s = 0; s < NS1; ++s) Z += pZ[s * T + t];
  sc2g[t] = SC2C - flog2(Z);
}

// --- pass 2: block = 128 codes (4 waves x 32 = 2 A-pairs), sweeps a
//     1024-row split. zhl staged (2x16KB dbuf); sc2 split (4KB) staged
//     once. Tile-skip per row-group: max(fb)+cc > -36. LDS 36KB. ---
__global__ __launch_bounds__(256, 4) void k_pass2(
    const short* __restrict__ ehl, const short* __restrict__ zhl,
    const float* __restrict__ sc2g,
    float* __restrict__ avg, float* __restrict__ scal) {
  const int tid = threadIdx.x;
  const int lane = tid & 63, wv = tid >> 6;
  const int q = lane >> 4, c = lane & 15;
  const int bx = blockIdx.x & 127, by = blockIdx.x >> 7;
  const int tb0 = by * (T / RS2);
  const int cbase = bx * 128 + wv * 32;
  const int NT = (T / RS2) / 16;    // 64
  const int NP = NT / PHT;          // 8

  __shared__ s16x8 dbuf[2][PHT * 128];   // 32KB
  __shared__ float sc2l[T / RS2];        // 1024 f = 4KB

  ((float4*)sc2l)[tid] = ((const float4*)(sc2g + tb0))[tid];

  const s16x8* eg = (const s16x8*)ehl;
  const int atile = cbase >> 4;
  s16x8 ah[2], al[2];
#pragma unroll
  for (int rg = 0; rg < 2; ++rg) {
    ah[rg] = eg[(atile + rg) * 128 + lane];
    al[rg] = eg[(atile + rg) * 128 + 64 + lane];
  }

  f32x4 sg;
#pragma unroll
  for (int r = 0; r < 4; ++r) sg[r] = NS2F;

  float accP[2][4], accE[2][4];
#pragma unroll
  for (int rg = 0; rg < 2; ++rg)
#pragma unroll
    for (int k = 0; k < 4; ++k) { accP[rg][k] = 0.f; accE[rg][k] = 0.f; }

  const s16x8* zt = (const s16x8*)zhl + (size_t)(tb0 >> 4) * 128;

#pragma unroll
  for (int j = 0; j < 4; ++j)
    gload16(zt + wv * 256 + j * 64 + lane, &dbuf[0][wv * 256 + j * 64]);
  __syncthreads();

  for (int p = 0; p < NP; ++p) {
    if (p + 1 < NP) {
      const s16x8* gs = zt + (p + 1) * (PHT * 128);
      s16x8* lb = &dbuf[(p + 1) & 1][0];
#pragma unroll
      for (int j = 0; j < 4; ++j)
        gload16(gs + wv * 256 + j * 64 + lane, lb + wv * 256 + j * 64);
    }
    const s16x8* bb = &dbuf[p & 1][0];
#pragma unroll
    for (int tt = 0; tt < PHT; ++tt) {
      s16x8 bh = bb[tt * 128 + lane], bl = bb[tt * 128 + 64 + lane];
      float cc = sc2l[(p * PHT + tt) * 16 + c];
#pragma unroll
      for (int rg = 0; rg < 2; ++rg) {
        f32x4 acc = __builtin_amdgcn_mfma_f32_16x16x32_bf16(ah[rg], bh, sg, 0, 0, 0);
        acc = __builtin_amdgcn_mfma_f32_16x16x32_bf16(al[rg], bh, acc, 0, 0, 0);
        acc = __builtin_amdgcn_mfma_f32_16x16x32_bf16(ah[rg], bl, acc, 0, 0, 0);

        float m4 = fmaxf(fmaxf(acc[0], acc[1]), fmaxf(acc[2], acc[3]));
        if (__any(m4 + cc > SKIPM)) {
#pragma unroll
          for (int r = 0; r < 4; ++r) {
            float dl = acc[r] + cc;   // fb - lse (<=0)
            float pe = fexp2(dl);     // underflow -> 0
            accP[rg][r] += pe;
            accE[rg][r] = fmaf(pe, dl, accE[rg][r]);
          }
        }
      }
    }
    __syncthreads();
  }

  float etot = 0.f;
#pragma unroll
  for (int rg = 0; rg < 2; ++rg)
#pragma unroll
    for (int k = 0; k < 4; ++k) etot += accE[rg][k];

#pragma unroll
  for (int d = 1; d < 16; d <<= 1) {
#pragma unroll
    for (int rg = 0; rg < 2; ++rg)
#pragma unroll
      for (int k = 0; k < 4; ++k) accP[rg][k] += __shfl_xor(accP[rg][k], d);
  }
#pragma unroll
  for (int rg = 0; rg < 2; ++rg)
#pragma unroll
    for (int k = 0; k < 4; ++k) {
      if (c == k) atomicAdd(&avg[cbase + rg * 16 + q * 4 + k], accP[rg][k]);
    }

  float* red = sc2l;                 // sweep done; reuse LDS (post-barrier)
  red[tid] = etot;
  __syncthreads();
  for (int st = 128; st > 0; st >>= 1) {
    if (tid < st) red[tid] += red[tid + st];
    __syncthreads();
  }
  if (tid == 0) atomicAdd(&scal[0], red[0]);
}

// --- merge-final: 32 blocks, thread = row. Top-2 combine, exact fp32
//     refine, vq sum + straight-through output; last block finals. ---
__global__ __launch_bounds__(256) void k_mf(
    const float* __restrict__ pm1, const float* __restrict__ pm2,
    const int* __restrict__ pi1, const int* __restrict__ pi2,
    const float* __restrict__ zf, const float* __restrict__ embn,
    const float* __restrict__ ses2, const float* __restrict__ a02,
    float* __restrict__ avg, float* __restrict__ scal, float* __restrict__ out) {
  const int tid = threadIdx.x;
  const int t = blockIdx.x * 256 + tid;
  __shared__ float red[256];
  __shared__ unsigned sord;

  float m1 = -1e30f, m2 = -1e30f;
  int i1 = 0, i2 = 0;
  for (int s = 0; s < NS1; ++s) {
    const int p = s * T + t;
    float sm1 = pm1[p], sm2 = pm2[p];
    int si1 = pi1[p], si2 = pi2[p];
    bool c1 = sm1 > m1;
    float lm = c1 ? m1 : sm1;
    int li = c1 ? i1 : si1;
    float nm1 = c1 ? sm1 : m1;
    int ni1 = c1 ? si1 : i1;
    bool cb = sm2 > m2;
    float mm2 = cb ? sm2 : m2;
    int mi2 = cb ? si2 : i2;
    bool c3 = mm2 > lm;
    m1 = nm1; i1 = ni1;
    m2 = c3 ? mm2 : lm;
    i2 = c3 ? mi2 : li;
  }
  const float a02t = a02[t];

  const float4* zr4 = (const float4*)(zf + (size_t)t * ED);
  float4 z0 = zr4[0], z1 = zr4[1], z2 = zr4[2], z3 = zr4[3];
  float4 z4 = zr4[4], z5 = zr4[5], z6 = zr4[6], z7 = zr4[7];
  float d1 = dot32x(embn + (size_t)i1 * ED, z0, z1, z2, z3, z4, z5, z6, z7);
  float d2 = dot32x(embn + (size_t)i2 * ED, z0, z1, z2, z3, z4, z5, z6, z7);
  float fb1 = fmaf(K2, d1, a02t + ses2[i1]);   // true a02/ses2: exact rule
  float fb2 = fmaf(K2, d2, a02t + ses2[i2]);
  int bi = (fb2 > fb1 || (fb2 == fb1 && i2 < i1)) ? i2 : i1;

  const int b = t >> 8, hw = t & 255;
  float* ob = out + (size_t)b * (ED * 256) + hw;
  float ss = 0.f;
  const float4* e4 = (const float4*)(embn + (size_t)bi * ED);
#pragma unroll
  for (int j = 0; j < 8; ++j) {
    float4 qv = e4[j];
    float4 zv = (j == 0) ? z0 : (j == 1) ? z1 : (j == 2) ? z2 : (j == 3) ? z3
              : (j == 4) ? z4 : (j == 5) ? z5 : (j == 6) ? z6 : z7;
    float df;
    df = qv.x - zv.x; ss = fmaf(df, df, ss); ob[(4 * j + 0) * 256] = zv.x + (qv.x - zv.x);
    df = qv.y - zv.y; ss = fmaf(df, df, ss); ob[(4 * j + 1) * 256] = zv.y + (qv.y - zv.y);
    df = qv.z - zv.z; ss = fmaf(df, df, ss); ob[(4 * j + 2) * 256] = zv.z + (qv.z - zv.z);
    df = qv.w - zv.w; ss = fmaf(df, df, ss); ob[(4 * j + 3) * 256] = zv.w + (qv.w - zv.w);
  }
  red[tid] = ss;
  __syncthreads();
  for (int st = 128; st > 0; st >>= 1) {
    if (tid < st) red[tid] += red[tid + st];
    __syncthreads();
  }
  if (tid == 0) atomicAdd(&scal[1], red[0]);

  // last-block final (avg/scal[0] were completed by the previous kernel)
  __threadfence();
  __syncthreads();
  if (tid == 0) sord = atomicAdd((unsigned*)&scal[2], 1u);
  __syncthreads();
  if (sord == 31) {
    float s = 0.f;
    for (int i = tid; i < N_E; i += 256) {
      float a = avg[i] * (1.0f / T);
      s += a * (flog2(a + 1e-5f) * LN2);
    }
    red[tid] = s;
    __syncthreads();
    for (int st = 128; st > 0; st >>= 1) {
      if (tid < st) red[tid] += red[tid + st];
      __syncthreads();
    }
    if (tid == 0) {
      float avg_entropy = -red[0];
      float se = scal[0];
      float vqs = __hip_atomic_load(&scal[1], __ATOMIC_RELAXED,
                                    __HIP_MEMORY_SCOPE_AGENT);
      float sample_entropy = -(se * LN2) * (1.0f / T);
      float vq = vqs * (1.0f / (T * ED));
      out[T * ED + 0] = vq;
      out[T * ED + 1] = 0.25f * vq;
      out[T * ED + 2] = 0.1f * (sample_entropy - avg_entropy);
    }
  }
}

extern "C" void kernel_launch(void* const* d_in, const int* in_sizes, int n_in,
                              void* d_out, int out_size, void* d_ws, size_t ws_size,
                              hipStream_t stream) {
  const float* z = (const float*)d_in[0];
  const float* emb = (const float*)d_in[1];
  float* out = (float*)d_out;
  float* w = (float*)d_ws;

  float* embn = w;                          // 524288 f
  float* ses2 = embn + 524288;              // 16384
  float* zf   = ses2 + 16384;               // 262144
  float* a02  = zf + 262144;                // 8192
  short* ehl  = (short*)(a02 + 8192);       // 1048576 sh (524288 f)
  short* zhl  = ehl + 1048576;              // 524288 sh  (262144 f)
  float* pm1  = (float*)(zhl + 524288);     // NS1*T = 131072 f
  float* pm2  = pm1 + NS1 * T;              // 131072
  float* pZ   = pm2 + NS1 * T;              // 131072
  int*   pi1  = (int*)(pZ + NS1 * T);       // 131072
  int*   pi2  = pi1 + NS1 * T;              // 131072
  float* avg  = (float*)(pi2 + NS1 * T);    // 16384
  float* scal = avg + 16384;                // 4: sampE, vq, counter, pad
  float* sc2g = scal + 4;                   // 8192

  k_prep<<<161, 256, 0, stream>>>(emb, z, embn, ses2, zf, a02, ehl, zhl,
                                  avg, scal);
  k_pass1<<<dim3(T / 128, NS1), 256, 0, stream>>>(ehl, zhl,
                                                  pm1, pm2, pZ, pi1, pi2);
  k_zred<<<T / 256, 256, 0, stream>>>(pZ, sc2g);
  k_pass2<<<(N_E / 128) * RS2, 256, 0, stream>>>(ehl, zhl, sc2g, avg, scal);
  k_mf<<<32, 256, 0, stream>>>(pm1, pm2, pi1, pi2, zf, embn, ses2, a02,
                               avg, scal, out);
}